// Round 8
// baseline (323.145 us; speedup 1.0000x reference)
//
#include <hip/hip_runtime.h>

typedef __attribute__((ext_vector_type(8))) short bf16x8;
typedef __attribute__((ext_vector_type(16))) float f32x16;

#define K_DIM 4096
#define N_DIM 4096
#define BM 256
#define BN 256
#define BK 64
#define NT (K_DIM / BK)   // 64 K-tiles
#define HALF (128 * BK)   // ushorts per half-tile (8192)
#define BOFF (BM * BK)    // B region offset within a buffer (16384 ushorts)

// ---------- helpers ----------

__device__ __forceinline__ unsigned short f2bf(float f) {
  union { float f; unsigned u; } c; c.f = f;
  unsigned u = c.u;
  return (unsigned short)((u + 0x7fffu + ((u >> 16) & 1u)) >> 16);  // RNE f32->bf16
}

__device__ __forceinline__ void gload16(const unsigned short* g, unsigned short* l) {
  __builtin_amdgcn_global_load_lds(
      (const __attribute__((address_space(1))) void*)g,
      (__attribute__((address_space(3))) void*)l,
      16, 0, 0);
}

// swizzled LDS fragment read: logical [row][64] bf16, byte ^= (row&7)<<4
__device__ __forceinline__ bf16x8 ldfrag_(const unsigned short* p, int row, int k8) {
  int o = row * BK + k8 * 8;      // ushort offset
  o ^= (row & 7) << 3;            // = byte ^ (row&7)<<4
  return *reinterpret_cast<const bf16x8*>(p + o);
}

// ---------- prep: 2:4 prune x (exact top_k tie rule) + cast bf16 ----------

__global__ void __launch_bounds__(256) prune_cast_x(const float* __restrict__ x,
                                                    unsigned short* __restrict__ xb,
                                                    long ngroups) {
  long stride = (long)gridDim.x * blockDim.x;
  for (long g = (long)blockIdx.x * blockDim.x + threadIdx.x; g < ngroups; g += stride) {
    float4 v = reinterpret_cast<const float4*>(x)[g];
    float vv[4] = {v.x, v.y, v.z, v.w};
    float av[4] = {fabsf(v.x), fabsf(v.y), fabsf(v.z), fabsf(v.w)};
    unsigned short o[4];
#pragma unroll
    for (int i = 0; i < 4; ++i) {
      int beats = 0;
#pragma unroll
      for (int j = 0; j < 4; ++j) {
        if (j == i) continue;
        beats += (av[j] > av[i] || (av[j] == av[i] && j < i)) ? 1 : 0;
      }
      o[i] = f2bf(beats < 2 ? vv[i] : 0.0f);
    }
    ushort4 pk; pk.x = o[0]; pk.y = o[1]; pk.z = o[2]; pk.w = o[3];
    reinterpret_cast<ushort4*>(xb)[g] = pk;
  }
}

__global__ void __launch_bounds__(256) cast_w(const float* __restrict__ w,
                                              unsigned short* __restrict__ wb,
                                              long ngroups) {
  long stride = (long)gridDim.x * blockDim.x;
  for (long g = (long)blockIdx.x * blockDim.x + threadIdx.x; g < ngroups; g += stride) {
    float4 v = reinterpret_cast<const float4*>(w)[g];
    ushort4 pk;
    pk.x = f2bf(v.x); pk.y = f2bf(v.y); pk.z = f2bf(v.z); pk.w = f2bf(v.w);
    reinterpret_cast<ushort4*>(wb)[g] = pk;
  }
}

// ---------- 256x256 GEMM: R2 sync skeleton (verified best) + 32x32x16 MFMA ----------
// R2 structure exactly: 4 phases/tile, dbuf LDS 128KiB, staging P1:A-h1(t+1),
// P2:B-h0(t+1), P3:B-h1(t+1), P4:A-h0(t+2), vmcnt(2) at P4 (R2's tail; R7's
// vmcnt(4) regressed). Change (R7->R8): MFMA 16x16x32 -> 32x32x16
// (ceiling 2075->2382 TF, 4x fewer MFMA instrs; LDS traffic identical).
// Frag layouts: A/B lane l: row/col=l&31, k = (l>>5)*8 + e (contiguous octet);
// C/D: col=lane&31, row=(reg&3)+8*(reg>>2)+4*(lane>>5), reg in [0,16).

// A quadrant MH: rows wrow0 + MH*64 + m_*32 + r32, k8 = ks*2 + kh  (8 reads)
#define LD_A32(LP, MH)                                                      \
  _Pragma("unroll") for (int m_ = 0; m_ < 2; ++m_)                          \
  _Pragma("unroll") for (int ks_ = 0; ks_ < 4; ++ks_)                       \
    a[m_][ks_] = ldfrag_((LP), wrow0 + (MH)*64 + m_*32 + r32, ks_*2 + kh);

// B quadrant NH: rows wcol0 + NH*32 + r32 (4 reads)
#define LD_B32(LP, NH, BV)                                                  \
  _Pragma("unroll") for (int ks_ = 0; ks_ < 4; ++ks_)                       \
    BV[ks_] = ldfrag_((LP) + BOFF, wcol0 + (NH)*32 + r32, ks_*2 + kh);

// 8 MFMA: 2 m-blocks x 4 k-steps into acc[MH*2+m_][NH]
#define QUAD32(MH, NH, BV)                                                  \
  _Pragma("unroll") for (int m_ = 0; m_ < 2; ++m_)                          \
  _Pragma("unroll") for (int ks_ = 0; ks_ < 4; ++ks_)                       \
    acc[(MH)*2 + m_][NH] = __builtin_amdgcn_mfma_f32_32x32x16_bf16(          \
        a[m_][ks_], BV[ks_], acc[(MH)*2 + m_][NH], 0, 0, 0);

#define STG(G, O0, O1, LP, KK)                                              \
  do { gload16((G) + (O0) + (KK), (LP) + l0);                               \
       gload16((G) + (O1) + (KK), (LP) + l1); } while (0)

__global__ void __launch_bounds__(512, 2) gemm256(const unsigned short* __restrict__ A,
                                                  const unsigned short* __restrict__ B,
                                                  float* __restrict__ C, int Mdim) {
  __shared__ unsigned short lds[2][2 * BM * BK];  // [buf][ A(16384) | B(16384) ]

  const int nbn = N_DIM / BN;                 // 16
  const int cpx = gridDim.x >> 3;             // grid % 8 == 0 (bijective XCD swizzle)
  const int bid = blockIdx.x;
  const int swz = (bid & 7) * cpx + (bid >> 3);
  const int bm = swz / nbn, bn = swz % nbn;

  const int tid = threadIdx.x;
  const int lane = tid & 63;
  const int wid = tid >> 6;
  const int wr = wid >> 2;                    // 0..1: M half
  const int wc = wid & 3;                     // 0..3: N quarter
  const int r32 = lane & 31;                  // 32x32 fragment row/col
  const int kh = lane >> 5;                   // k-octet half 0..1
  const int wrow0 = wr * 128;
  const int wcol0 = wc * 64;

  // staging: 1024 chunks of 16B per half-tile; thread covers chunks tid, tid+512.
  // linear LDS dest; inverse-swizzled global source (involution: c ^= (c>>3)&7)
  const int c0 = tid, c1 = tid + 512;
  const int s0 = c0 ^ ((c0 >> 3) & 7);
  const int s1 = c1 ^ ((c1 >> 3) & 7);
  const int l0 = c0 * 8, l1 = c1 * 8;         // lds ushort offsets within half
  const size_t aRow = (size_t)bm * BM, bRow = (size_t)bn * BN;
  const size_t gA00 = (aRow +       (s0 >> 3)) * K_DIM + (s0 & 7) * 8;
  const size_t gA01 = (aRow +       (s1 >> 3)) * K_DIM + (s1 & 7) * 8;
  const size_t gA10 = (aRow + 128 + (s0 >> 3)) * K_DIM + (s0 & 7) * 8;
  const size_t gA11 = (aRow + 128 + (s1 >> 3)) * K_DIM + (s1 & 7) * 8;
  const size_t gB00 = (bRow +       (s0 >> 3)) * K_DIM + (s0 & 7) * 8;
  const size_t gB01 = (bRow +       (s1 >> 3)) * K_DIM + (s1 & 7) * 8;
  const size_t gB10 = (bRow + 128 + (s0 >> 3)) * K_DIM + (s0 & 7) * 8;
  const size_t gB11 = (bRow + 128 + (s1 >> 3)) * K_DIM + (s1 & 7) * 8;

  bf16x8 a[2][4], b0[4], b1[4];
  f32x16 acc[4][2] = {};

  // prologue (R2 exact): tile0 full + tile1 A-h0; vmcnt(2)
  STG(A, gA00, gA01, &lds[0][0], 0);
  STG(A, gA10, gA11, &lds[0][HALF], 0);
  STG(B, gB00, gB01, &lds[0][BOFF], 0);
  STG(B, gB10, gB11, &lds[0][BOFF + HALF], 0);
  STG(A, gA00, gA01, &lds[1][0], BK);
  asm volatile("s_waitcnt vmcnt(2)" ::: "memory");
  __builtin_amdgcn_s_barrier();

  for (int t = 0; t < NT; ++t) {
    unsigned short* Lc = lds[t & 1];
    unsigned short* Ln = lds[(t & 1) ^ 1];
    const int k1 = ((t + 1) & (NT - 1)) * BK;  // wraps at tail: redundant, harmless
    const int k2 = ((t + 2) & (NT - 1)) * BK;

    // P1: A[mh0] + B[nh0] reads (12); stage A-h1(t+1); quadrant (0,0)
    LD_A32(Lc, 0);
    LD_B32(Lc, 0, b0);
    STG(A, gA10, gA11, Ln + HALF, k1);
    __builtin_amdgcn_s_barrier();
    asm volatile("s_waitcnt lgkmcnt(0)" ::: "memory");
    __builtin_amdgcn_s_setprio(1);
    QUAD32(0, 0, b0);
    __builtin_amdgcn_s_setprio(0);
    __builtin_amdgcn_s_barrier();

    // P2: B[nh1] reads (4); stage B-h0(t+1); quadrant (0,1)
    LD_B32(Lc, 1, b1);
    STG(B, gB00, gB01, Ln + BOFF, k1);
    __builtin_amdgcn_s_barrier();
    asm volatile("s_waitcnt lgkmcnt(0)" ::: "memory");
    __builtin_amdgcn_s_setprio(1);
    QUAD32(0, 1, b1);
    __builtin_amdgcn_s_setprio(0);
    __builtin_amdgcn_s_barrier();

    // P3: A[mh1] reads (8); stage B-h1(t+1); quadrant (1,1)
    LD_A32(Lc, 1);
    STG(B, gB10, gB11, Ln + BOFF + HALF, k1);
    __builtin_amdgcn_s_barrier();
    asm volatile("s_waitcnt lgkmcnt(0)" ::: "memory");
    __builtin_amdgcn_s_setprio(1);
    QUAD32(1, 1, b1);
    __builtin_amdgcn_s_setprio(0);
    __builtin_amdgcn_s_barrier();

    // P4: no ds_reads (b0 live from P1); stage A-h0(t+2) into current buffer
    //     (A reads of Lc drained at P3); quadrant (1,0); vmcnt(2) (R2 exact)
    STG(A, gA00, gA01, Lc, k2);
    __builtin_amdgcn_s_barrier();
    __builtin_amdgcn_s_setprio(1);
    QUAD32(1, 0, b0);
    __builtin_amdgcn_s_setprio(0);
    asm volatile("s_waitcnt vmcnt(2)" ::: "memory");
    __builtin_amdgcn_s_barrier();
  }

  // epilogue: 32x32 C/D layout col=lane&31, row=(reg&3)+8*(reg>>2)+4*(lane>>5)
  const int rb = bm * BM + wrow0;
  const int cb = bn * BN + wcol0 + r32;
#pragma unroll
  for (int mi = 0; mi < 4; ++mi)
#pragma unroll
    for (int ni = 0; ni < 2; ++ni) {
      const int col = cb + ni * 32;
#pragma unroll
      for (int reg = 0; reg < 16; ++reg) {
        const int row = rb + mi * 32 + (reg & 3) + 8 * (reg >> 2) + 4 * kh;
        C[(size_t)row * N_DIM + col] = acc[mi][ni][reg];
      }
    }
}

// ---------- launch ----------

extern "C" void kernel_launch(void* const* d_in, const int* in_sizes, int n_in,
                              void* d_out, int out_size, void* d_ws, size_t ws_size,
                              hipStream_t stream) {
  const float* x = (const float*)d_in[0];
  const float* w = (const float*)d_in[1];
  float* out = (float*)d_out;

  const int Mdim = in_sizes[0] / K_DIM;        // 8192
  const long xGroups = (long)in_sizes[0] / 4;
  const long wGroups = (long)in_sizes[1] / 4;

  unsigned short* xb = (unsigned short*)d_ws;              // M*K bf16 (64 MB)
  unsigned short* wb = xb + (size_t)Mdim * K_DIM;          // N*K bf16 (32 MB)

  prune_cast_x<<<2048, 256, 0, stream>>>(x, xb, xGroups);
  cast_w<<<1024, 256, 0, stream>>>(w, wb, wGroups);

  const int grid = (Mdim / BM) * (N_DIM / BN);             // 32 * 16 = 512
  gemm256<<<grid, 512, 0, stream>>>(xb, wb, out, Mdim);
}

// Round 9
// 311.639 us; speedup vs baseline: 1.0369x; 1.0369x over previous
//
#include <hip/hip_runtime.h>

typedef __attribute__((ext_vector_type(8))) short bf16x8;
typedef __attribute__((ext_vector_type(16))) float f32x16;

#define K_DIM 4096
#define N_DIM 4096
#define BM 256
#define BN 256
#define BK 64
#define NT (K_DIM / BK)   // 64 K-tiles
#define HALF (128 * BK)   // ushorts per half-tile (8192)
#define BOFF (BM * BK)    // B region offset within a buffer (16384 ushorts)

// ---------- helpers ----------

__device__ __forceinline__ unsigned short f2bf(float f) {
  union { float f; unsigned u; } c; c.f = f;
  unsigned u = c.u;
  return (unsigned short)((u + 0x7fffu + ((u >> 16) & 1u)) >> 16);  // RNE f32->bf16
}

__device__ __forceinline__ void gload16(const unsigned short* g, unsigned short* l) {
  __builtin_amdgcn_global_load_lds(
      (const __attribute__((address_space(1))) void*)g,
      (__attribute__((address_space(3))) void*)l,
      16, 0, 0);
}

// swizzle v2 (R8->R9): slot = k8 ^ (row&7) ^ ((row>>3)&3).
// Row bits 3-4 now discriminate lanes {l,l+8,l+16,l+24} which read the same
// k8 in the 32x32 fragment pattern (they collided 4-way under v1).
__device__ __forceinline__ bf16x8 ldfrag_(const unsigned short* p, int row, int k8) {
  int o = row * BK + k8 * 8;                         // ushort offset
  o ^= (((row & 7) ^ ((row >> 3) & 3)) << 3);        // slot XOR (16B units)
  return *reinterpret_cast<const bf16x8*>(p + o);
}

// ---------- prep: 2:4 prune x (exact top_k tie rule) + cast bf16 ----------

__global__ void __launch_bounds__(256) prune_cast_x(const float* __restrict__ x,
                                                    unsigned short* __restrict__ xb,
                                                    long ngroups) {
  long stride = (long)gridDim.x * blockDim.x;
  for (long g = (long)blockIdx.x * blockDim.x + threadIdx.x; g < ngroups; g += stride) {
    float4 v = reinterpret_cast<const float4*>(x)[g];
    float vv[4] = {v.x, v.y, v.z, v.w};
    float av[4] = {fabsf(v.x), fabsf(v.y), fabsf(v.z), fabsf(v.w)};
    unsigned short o[4];
#pragma unroll
    for (int i = 0; i < 4; ++i) {
      int beats = 0;
#pragma unroll
      for (int j = 0; j < 4; ++j) {
        if (j == i) continue;
        beats += (av[j] > av[i] || (av[j] == av[i] && j < i)) ? 1 : 0;
      }
      o[i] = f2bf(beats < 2 ? vv[i] : 0.0f);
    }
    ushort4 pk; pk.x = o[0]; pk.y = o[1]; pk.z = o[2]; pk.w = o[3];
    reinterpret_cast<ushort4*>(xb)[g] = pk;
  }
}

__global__ void __launch_bounds__(256) cast_w(const float* __restrict__ w,
                                              unsigned short* __restrict__ wb,
                                              long ngroups) {
  long stride = (long)gridDim.x * blockDim.x;
  for (long g = (long)blockIdx.x * blockDim.x + threadIdx.x; g < ngroups; g += stride) {
    float4 v = reinterpret_cast<const float4*>(w)[g];
    ushort4 pk;
    pk.x = f2bf(v.x); pk.y = f2bf(v.y); pk.z = f2bf(v.z); pk.w = f2bf(v.w);
    reinterpret_cast<ushort4*>(wb)[g] = pk;
  }
}

// ---------- 256x256 GEMM: R2 sync skeleton + 32x32x16 MFMA + swizzle v2 ----------
// Frag layouts (verified R8, absmax 0.03125): A/B lane l: row/col=l&31,
// k=(l>>5)*8+e; C/D: col=lane&31, row=(reg&3)+8*(reg>>2)+4*(lane>>5).

// A quadrant MH: rows wrow0 + MH*64 + m_*32 + r32, k8 = ks*2 + kh  (8 reads)
#define LD_A32(LP, MH)                                                      \
  _Pragma("unroll") for (int m_ = 0; m_ < 2; ++m_)                          \
  _Pragma("unroll") for (int ks_ = 0; ks_ < 4; ++ks_)                       \
    a[m_][ks_] = ldfrag_((LP), wrow0 + (MH)*64 + m_*32 + r32, ks_*2 + kh);

// B quadrant NH: rows wcol0 + NH*32 + r32 (4 reads)
#define LD_B32(LP, NH, BV)                                                  \
  _Pragma("unroll") for (int ks_ = 0; ks_ < 4; ++ks_)                       \
    BV[ks_] = ldfrag_((LP) + BOFF, wcol0 + (NH)*32 + r32, ks_*2 + kh);

// 8 MFMA: 2 m-blocks x 4 k-steps into acc[MH*2+m_][NH]
#define QUAD32(MH, NH, BV)                                                  \
  _Pragma("unroll") for (int m_ = 0; m_ < 2; ++m_)                          \
  _Pragma("unroll") for (int ks_ = 0; ks_ < 4; ++ks_)                       \
    acc[(MH)*2 + m_][NH] = __builtin_amdgcn_mfma_f32_32x32x16_bf16(          \
        a[m_][ks_], BV[ks_], acc[(MH)*2 + m_][NH], 0, 0, 0);

#define STG(G, O0, O1, LP, KK)                                              \
  do { gload16((G) + (O0) + (KK), (LP) + l0);                               \
       gload16((G) + (O1) + (KK), (LP) + l1); } while (0)

__global__ void __launch_bounds__(512, 2) gemm256(const unsigned short* __restrict__ A,
                                                  const unsigned short* __restrict__ B,
                                                  float* __restrict__ C, int Mdim) {
  __shared__ unsigned short lds[2][2 * BM * BK];  // [buf][ A(16384) | B(16384) ]

  const int nbn = N_DIM / BN;                 // 16
  const int cpx = gridDim.x >> 3;             // grid % 8 == 0 (bijective XCD swizzle)
  const int bid = blockIdx.x;
  const int swz = (bid & 7) * cpx + (bid >> 3);
  const int bm = swz / nbn, bn = swz % nbn;

  const int tid = threadIdx.x;
  const int lane = tid & 63;
  const int wid = tid >> 6;
  const int wr = wid >> 2;                    // 0..1: M half
  const int wc = wid & 3;                     // 0..3: N quarter
  const int r32 = lane & 31;                  // 32x32 fragment row/col
  const int kh = lane >> 5;                   // k-octet half 0..1
  const int wrow0 = wr * 128;
  const int wcol0 = wc * 64;

  // staging: 1024 chunks of 16B per half-tile; thread covers chunks tid, tid+512.
  // linear LDS dest; inverse-swizzled global source — swizzle v2 involution:
  // s = c ^ ((c>>3)&7) ^ ((c>>6)&3)   (c bits 3-9 = lrow; flips only bits 0-2)
  const int c0 = tid, c1 = tid + 512;
  const int s0 = c0 ^ ((c0 >> 3) & 7) ^ ((c0 >> 6) & 3);
  const int s1 = c1 ^ ((c1 >> 3) & 7) ^ ((c1 >> 6) & 3);
  const int l0 = c0 * 8, l1 = c1 * 8;         // lds ushort offsets within half
  const size_t aRow = (size_t)bm * BM, bRow = (size_t)bn * BN;
  const size_t gA00 = (aRow +       (s0 >> 3)) * K_DIM + (s0 & 7) * 8;
  const size_t gA01 = (aRow +       (s1 >> 3)) * K_DIM + (s1 & 7) * 8;
  const size_t gA10 = (aRow + 128 + (s0 >> 3)) * K_DIM + (s0 & 7) * 8;
  const size_t gA11 = (aRow + 128 + (s1 >> 3)) * K_DIM + (s1 & 7) * 8;
  const size_t gB00 = (bRow +       (s0 >> 3)) * K_DIM + (s0 & 7) * 8;
  const size_t gB01 = (bRow +       (s1 >> 3)) * K_DIM + (s1 & 7) * 8;
  const size_t gB10 = (bRow + 128 + (s0 >> 3)) * K_DIM + (s0 & 7) * 8;
  const size_t gB11 = (bRow + 128 + (s1 >> 3)) * K_DIM + (s1 & 7) * 8;

  bf16x8 a[2][4], b0[4], b1[4];
  f32x16 acc[4][2] = {};

  // prologue (R2 exact): tile0 full + tile1 A-h0; vmcnt(2)
  STG(A, gA00, gA01, &lds[0][0], 0);
  STG(A, gA10, gA11, &lds[0][HALF], 0);
  STG(B, gB00, gB01, &lds[0][BOFF], 0);
  STG(B, gB10, gB11, &lds[0][BOFF + HALF], 0);
  STG(A, gA00, gA01, &lds[1][0], BK);
  asm volatile("s_waitcnt vmcnt(2)" ::: "memory");
  __builtin_amdgcn_s_barrier();

  for (int t = 0; t < NT; ++t) {
    unsigned short* Lc = lds[t & 1];
    unsigned short* Ln = lds[(t & 1) ^ 1];
    const int k1 = ((t + 1) & (NT - 1)) * BK;  // wraps at tail: redundant, harmless
    const int k2 = ((t + 2) & (NT - 1)) * BK;

    // P1: A[mh0] + B[nh0] reads (12); stage A-h1(t+1); quadrant (0,0)
    LD_A32(Lc, 0);
    LD_B32(Lc, 0, b0);
    STG(A, gA10, gA11, Ln + HALF, k1);
    __builtin_amdgcn_s_barrier();
    asm volatile("s_waitcnt lgkmcnt(0)" ::: "memory");
    __builtin_amdgcn_s_setprio(1);
    QUAD32(0, 0, b0);
    __builtin_amdgcn_s_setprio(0);
    __builtin_amdgcn_s_barrier();

    // P2: B[nh1] reads (4); stage B-h0(t+1); quadrant (0,1)
    LD_B32(Lc, 1, b1);
    STG(B, gB00, gB01, Ln + BOFF, k1);
    __builtin_amdgcn_s_barrier();
    asm volatile("s_waitcnt lgkmcnt(0)" ::: "memory");
    __builtin_amdgcn_s_setprio(1);
    QUAD32(0, 1, b1);
    __builtin_amdgcn_s_setprio(0);
    __builtin_amdgcn_s_barrier();

    // P3: A[mh1] reads (8); stage B-h1(t+1); quadrant (1,1)
    LD_A32(Lc, 1);
    STG(B, gB10, gB11, Ln + BOFF + HALF, k1);
    __builtin_amdgcn_s_barrier();
    asm volatile("s_waitcnt lgkmcnt(0)" ::: "memory");
    __builtin_amdgcn_s_setprio(1);
    QUAD32(1, 1, b1);
    __builtin_amdgcn_s_setprio(0);
    __builtin_amdgcn_s_barrier();

    // P4: no ds_reads (b0 live from P1); stage A-h0(t+2) into current buffer
    //     (A reads of Lc drained at P3); quadrant (1,0); vmcnt(2) (R2 exact)
    STG(A, gA00, gA01, Lc, k2);
    __builtin_amdgcn_s_barrier();
    __builtin_amdgcn_s_setprio(1);
    QUAD32(1, 0, b0);
    __builtin_amdgcn_s_setprio(0);
    asm volatile("s_waitcnt vmcnt(2)" ::: "memory");
    __builtin_amdgcn_s_barrier();
  }

  // epilogue: 32x32 C/D layout col=lane&31, row=(reg&3)+8*(reg>>2)+4*(lane>>5)
  const int rb = bm * BM + wrow0;
  const int cb = bn * BN + wcol0 + r32;
#pragma unroll
  for (int mi = 0; mi < 4; ++mi)
#pragma unroll
    for (int ni = 0; ni < 2; ++ni) {
      const int col = cb + ni * 32;
#pragma unroll
      for (int reg = 0; reg < 16; ++reg) {
        const int row = rb + mi * 32 + (reg & 3) + 8 * (reg >> 2) + 4 * kh;
        C[(size_t)row * N_DIM + col] = acc[mi][ni][reg];
      }
    }
}

// ---------- launch ----------

extern "C" void kernel_launch(void* const* d_in, const int* in_sizes, int n_in,
                              void* d_out, int out_size, void* d_ws, size_t ws_size,
                              hipStream_t stream) {
  const float* x = (const float*)d_in[0];
  const float* w = (const float*)d_in[1];
  float* out = (float*)d_out;

  const int Mdim = in_sizes[0] / K_DIM;        // 8192
  const long xGroups = (long)in_sizes[0] / 4;
  const long wGroups = (long)in_sizes[1] / 4;

  unsigned short* xb = (unsigned short*)d_ws;              // M*K bf16 (64 MB)
  unsigned short* wb = xb + (size_t)Mdim * K_DIM;          // N*K bf16 (32 MB)

  prune_cast_x<<<2048, 256, 0, stream>>>(x, xb, xGroups);
  cast_w<<<1024, 256, 0, stream>>>(w, wb, wGroups);

  const int grid = (Mdim / BM) * (N_DIM / BN);             // 32 * 16 = 512
  gemm256<<<grid, 512, 0, stream>>>(xb, wb, out, Mdim);
}

// Round 10
// 198.294 us; speedup vs baseline: 1.6296x; 1.5716x over previous
//
#include <hip/hip_runtime.h>

typedef __attribute__((ext_vector_type(4))) int i32x4;
typedef __attribute__((ext_vector_type(16))) int i32x16;

#define K_ELEMS 4096
#define N_DIM 4096
#define BM 256
#define BN 256
#define BKB 128            // K-bytes (=elems) per tile row: same 128B geometry as R9
#define NT (K_ELEMS / BKB) // 32 K-tiles
#define HALF (128 * BKB)   // bytes per half-tile region (16384)
#define BOFF (BM * BKB)    // B region offset within a buffer (32768 bytes)

// ---------- helpers ----------

__device__ __forceinline__ void gload16(const signed char* g, signed char* l) {
  __builtin_amdgcn_global_load_lds(
      (const __attribute__((address_space(1))) void*)g,
      (__attribute__((address_space(3))) void*)l,
      16, 0, 0);
}

// swizzle v2 (validated R9: 0 bank conflicts, byte-identical geometry):
// 16B-slot index ^= (row&7) ^ ((row>>3)&3)
__device__ __forceinline__ i32x4 ldfrag_(const signed char* p, int row, int c16) {
  int o = row * BKB + ((c16 ^ ((row & 7) ^ ((row >> 3) & 3))) << 4);
  return *reinterpret_cast<const i32x4*>(p + o);
}

// ---------- prep: prune (x only, exact top_k tie rule) + per-row i8 quantize ----------

template <bool PRUNE>
__global__ void __launch_bounds__(256) quant_rows(const float* __restrict__ in,
                                                  signed char* __restrict__ q,
                                                  float* __restrict__ scale) {
  const int row = blockIdx.x;
  const float4* rf = reinterpret_cast<const float4*>(in + (size_t)row * K_ELEMS);
  float4 vals[4];
  float m = 0.f;
#pragma unroll
  for (int i = 0; i < 4; ++i) {
    float4 v = rf[threadIdx.x + i * 256];   // one float4 == one 2:4 group
    if (PRUNE) {
      float vv[4] = {v.x, v.y, v.z, v.w};
      float av[4] = {fabsf(v.x), fabsf(v.y), fabsf(v.z), fabsf(v.w)};
      float o[4];
#pragma unroll
      for (int e = 0; e < 4; ++e) {
        int beats = 0;
#pragma unroll
        for (int j = 0; j < 4; ++j) {
          if (j == e) continue;
          beats += (av[j] > av[e] || (av[j] == av[e] && j < e)) ? 1 : 0;
        }
        o[e] = (beats < 2) ? vv[e] : 0.0f;
      }
      v.x = o[0]; v.y = o[1]; v.z = o[2]; v.w = o[3];
    }
    vals[i] = v;
    m = fmaxf(m, fmaxf(fmaxf(fabsf(v.x), fabsf(v.y)), fmaxf(fabsf(v.z), fabsf(v.w))));
  }
  // block max: wave64 butterfly then LDS across 4 waves
#pragma unroll
  for (int off = 32; off; off >>= 1) m = fmaxf(m, __shfl_xor(m, off));
  __shared__ float red[4];
  if ((threadIdx.x & 63) == 0) red[threadIdx.x >> 6] = m;
  __syncthreads();
  const float rm = fmaxf(fmaxf(red[0], red[1]), fmaxf(red[2], red[3]));
  const float inv = rm > 0.f ? 127.0f / rm : 0.f;
  if (threadIdx.x == 0) scale[row] = rm * (1.0f / 127.0f);
  int* qo = reinterpret_cast<int*>(q + (size_t)row * K_ELEMS);
#pragma unroll
  for (int i = 0; i < 4; ++i) {
    int q0 = __float2int_rn(vals[i].x * inv);
    int q1 = __float2int_rn(vals[i].y * inv);
    int q2 = __float2int_rn(vals[i].z * inv);
    int q3 = __float2int_rn(vals[i].w * inv);
    qo[threadIdx.x + i * 256] = (q0 & 255) | ((q1 & 255) << 8) | ((q2 & 255) << 16) | (q3 << 24);
  }
}

// ---------- 256x256 i8 GEMM: R9 skeleton verbatim, bytes instead of ushorts ----------
// mfma_i32_32x32x32_i8: A/B 16 i8/lane (4 VGPR), lane l: row/col=l&31,
// k=(l>>5)*16+e (natural extension of verified 8-elem bf16 mapping);
// C/D: col=lane&31, row=(reg&3)+8*(reg>>2)+4*(lane>>5) (dtype-independent).

#define LD_A32(LP, MH)                                                      \
  _Pragma("unroll") for (int m_ = 0; m_ < 2; ++m_)                          \
  _Pragma("unroll") for (int ks_ = 0; ks_ < 4; ++ks_)                       \
    a[m_][ks_] = ldfrag_((LP), wrow0 + (MH)*64 + m_*32 + r32, ks_*2 + kh);

#define LD_B32(LP, NH, BV)                                                  \
  _Pragma("unroll") for (int ks_ = 0; ks_ < 4; ++ks_)                       \
    BV[ks_] = ldfrag_((LP) + BOFF, wcol0 + (NH)*32 + r32, ks_*2 + kh);

#define QUAD32(MH, NH, BV)                                                  \
  _Pragma("unroll") for (int m_ = 0; m_ < 2; ++m_)                          \
  _Pragma("unroll") for (int ks_ = 0; ks_ < 4; ++ks_)                       \
    acc[(MH)*2 + m_][NH] = __builtin_amdgcn_mfma_i32_32x32x32_i8(            \
        a[m_][ks_], BV[ks_], acc[(MH)*2 + m_][NH], 0, 0, 0);

#define STG(G, O0, O1, LP, KK)                                              \
  do { gload16((G) + (O0) + (KK), (LP) + l0);                               \
       gload16((G) + (O1) + (KK), (LP) + l1); } while (0)

__global__ void __launch_bounds__(512, 2) gemm256(const signed char* __restrict__ A,
                                                  const signed char* __restrict__ B,
                                                  const float* __restrict__ sx,
                                                  const float* __restrict__ sw,
                                                  float* __restrict__ C) {
  __shared__ signed char lds[2][2 * BM * BKB];  // [buf][ A(32768) | B(32768) ] bytes

  const int nbn = N_DIM / BN;                 // 16
  const int cpx = gridDim.x >> 3;             // grid % 8 == 0 (bijective XCD swizzle)
  const int bid = blockIdx.x;
  const int swz = (bid & 7) * cpx + (bid >> 3);
  const int bm = swz / nbn, bn = swz % nbn;

  const int tid = threadIdx.x;
  const int lane = tid & 63;
  const int wid = tid >> 6;
  const int wr = wid >> 2;                    // 0..1: M half
  const int wc = wid & 3;                     // 0..3: N quarter
  const int r32 = lane & 31;
  const int kh = lane >> 5;                   // k 16-byte half 0..1
  const int wrow0 = wr * 128;
  const int wcol0 = wc * 64;

  // staging: 1024 x 16B chunks per half-tile; thread covers chunks tid, tid+512.
  // linear LDS dest; inverse-swizzled global source (same involution as read)
  const int c0 = tid, c1 = tid + 512;
  const int s0 = c0 ^ ((c0 >> 3) & 7) ^ ((c0 >> 6) & 3);
  const int s1 = c1 ^ ((c1 >> 3) & 7) ^ ((c1 >> 6) & 3);
  const int l0 = c0 * 16, l1 = c1 * 16;       // lds byte offsets within half
  const size_t aRow = (size_t)bm * BM, bRow = (size_t)bn * BN;
  const size_t gA00 = (aRow +       (s0 >> 3)) * K_ELEMS + (s0 & 7) * 16;
  const size_t gA01 = (aRow +       (s1 >> 3)) * K_ELEMS + (s1 & 7) * 16;
  const size_t gA10 = (aRow + 128 + (s0 >> 3)) * K_ELEMS + (s0 & 7) * 16;
  const size_t gA11 = (aRow + 128 + (s1 >> 3)) * K_ELEMS + (s1 & 7) * 16;
  const size_t gB00 = (bRow +       (s0 >> 3)) * K_ELEMS + (s0 & 7) * 16;
  const size_t gB01 = (bRow +       (s1 >> 3)) * K_ELEMS + (s1 & 7) * 16;
  const size_t gB10 = (bRow + 128 + (s0 >> 3)) * K_ELEMS + (s0 & 7) * 16;
  const size_t gB11 = (bRow + 128 + (s1 >> 3)) * K_ELEMS + (s1 & 7) * 16;

  i32x4 a[2][4], b0[4], b1[4];
  i32x16 acc[4][2] = {};

  // prologue (R2/R9 exact): tile0 full + tile1 A-h0; vmcnt(2)
  STG(A, gA00, gA01, &lds[0][0], 0);
  STG(A, gA10, gA11, &lds[0][HALF], 0);
  STG(B, gB00, gB01, &lds[0][BOFF], 0);
  STG(B, gB10, gB11, &lds[0][BOFF + HALF], 0);
  STG(A, gA00, gA01, &lds[1][0], BKB);
  asm volatile("s_waitcnt vmcnt(2)" ::: "memory");
  __builtin_amdgcn_s_barrier();

  for (int t = 0; t < NT; ++t) {
    signed char* Lc = lds[t & 1];
    signed char* Ln = lds[(t & 1) ^ 1];
    const int k1 = ((t + 1) & (NT - 1)) * BKB;  // tail wrap: redundant, harmless
    const int k2 = ((t + 2) & (NT - 1)) * BKB;

    // P1: A[mh0] + B[nh0] reads (12); stage A-h1(t+1); quadrant (0,0)
    LD_A32(Lc, 0);
    LD_B32(Lc, 0, b0);
    STG(A, gA10, gA11, Ln + HALF, k1);
    __builtin_amdgcn_s_barrier();
    asm volatile("s_waitcnt lgkmcnt(0)" ::: "memory");
    __builtin_amdgcn_s_setprio(1);
    QUAD32(0, 0, b0);
    __builtin_amdgcn_s_setprio(0);
    __builtin_amdgcn_s_barrier();

    // P2: B[nh1] reads (4); stage B-h0(t+1); quadrant (0,1)
    LD_B32(Lc, 1, b1);
    STG(B, gB00, gB01, Ln + BOFF, k1);
    __builtin_amdgcn_s_barrier();
    asm volatile("s_waitcnt lgkmcnt(0)" ::: "memory");
    __builtin_amdgcn_s_setprio(1);
    QUAD32(0, 1, b1);
    __builtin_amdgcn_s_setprio(0);
    __builtin_amdgcn_s_barrier();

    // P3: A[mh1] reads (8); stage B-h1(t+1); quadrant (1,1)
    LD_A32(Lc, 1);
    STG(B, gB10, gB11, Ln + BOFF + HALF, k1);
    __builtin_amdgcn_s_barrier();
    asm volatile("s_waitcnt lgkmcnt(0)" ::: "memory");
    __builtin_amdgcn_s_setprio(1);
    QUAD32(1, 1, b1);
    __builtin_amdgcn_s_setprio(0);
    __builtin_amdgcn_s_barrier();

    // P4: no ds_reads (b0 live from P1); stage A-h0(t+2); quadrant (1,0); vmcnt(2)
    STG(A, gA00, gA01, Lc, k2);
    __builtin_amdgcn_s_barrier();
    __builtin_amdgcn_s_setprio(1);
    QUAD32(1, 0, b0);
    __builtin_amdgcn_s_setprio(0);
    asm volatile("s_waitcnt vmcnt(2)" ::: "memory");
    __builtin_amdgcn_s_barrier();
  }

  // epilogue: dequant out = acc * sx[row] * sw[col]
  const int rb = bm * BM + wrow0;
  const int cb = bn * BN + wcol0 + r32;
#pragma unroll
  for (int mi = 0; mi < 4; ++mi)
#pragma unroll
    for (int ni = 0; ni < 2; ++ni) {
      const int col = cb + ni * 32;
      const float swc = sw[col];
#pragma unroll
      for (int reg = 0; reg < 16; ++reg) {
        const int row = rb + mi * 32 + (reg & 3) + 8 * (reg >> 2) + 4 * kh;
        C[(size_t)row * N_DIM + col] = (float)acc[mi][ni][reg] * sx[row] * swc;
      }
    }
}

// ---------- launch ----------

extern "C" void kernel_launch(void* const* d_in, const int* in_sizes, int n_in,
                              void* d_out, int out_size, void* d_ws, size_t ws_size,
                              hipStream_t stream) {
  const float* x = (const float*)d_in[0];
  const float* w = (const float*)d_in[1];
  float* out = (float*)d_out;

  const int Mdim = in_sizes[0] / K_ELEMS;      // 8192
  const int Ndim = in_sizes[1] / K_ELEMS;      // 4096

  signed char* xq = (signed char*)d_ws;                          // 32 MB
  signed char* wq = xq + (size_t)Mdim * K_ELEMS;                 // 16 MB
  float* sx = (float*)(wq + (size_t)Ndim * K_ELEMS);             // 32 KB
  float* sw = sx + Mdim;                                         // 16 KB

  quant_rows<true><<<Mdim, 256, 0, stream>>>(x, xq, sx);
  quant_rows<false><<<Ndim, 256, 0, stream>>>(w, wq, sw);

  const int grid = (Mdim / BM) * (N_DIM / BN);                   // 32 * 16 = 512
  gemm256<<<grid, 512, 0, stream>>>(xq, wq, sx, sw, out);
}